// Round 1
// baseline (3381.873 us; speedup 1.0000x reference)
//
#include <hip/hip_runtime.h>
#include <math.h>

#define NNODES 100000
#define NEDGES 3200000
#define NFEAT  500
#define HID    64
#define NCLS   40
#define NLAYERS 8

// h = relu(x @ W + b); one wave per node, lane = out feature.
__global__ __launch_bounds__(256) void lin0_kernel(const float* __restrict__ x,
    const float* __restrict__ w, const float* __restrict__ b, float* __restrict__ h0)
{
    const int m = threadIdx.x >> 6, j = threadIdx.x & 63;
    const long n = (long)blockIdx.x * 4 + m;
    const float4* xrow = (const float4*)(x + n * NFEAT);   // 2000B rows, 16B aligned
    float acc = b[j];
#pragma unroll 5
    for (int k4 = 0; k4 < NFEAT / 4; ++k4) {
        const float4 xv = xrow[k4];                        // broadcast across wave
        const int k = k4 * 4;
        acc = fmaf(xv.x, w[(k + 0) * HID + j], acc);
        acc = fmaf(xv.y, w[(k + 1) * HID + j], acc);
        acc = fmaf(xv.z, w[(k + 2) * HID + j], acc);
        acc = fmaf(xv.w, w[(k + 3) * HID + j], acc);
    }
    h0[n * HID + j] = fmaxf(acc, 0.f);
}

__global__ __launch_bounds__(256) void count_kernel(const int* __restrict__ dst,
                                                    int* __restrict__ deg)
{
    int e = blockIdx.x * 256 + threadIdx.x;
    if (e < NEDGES) atomicAdd(&deg[dst[e]], 1);
}

__global__ __launch_bounds__(1024) void chunk_sum_kernel(const int* __restrict__ deg,
                                                         int* __restrict__ csum)
{
    __shared__ int s[1024];
    int i = blockIdx.x * 1024 + threadIdx.x;
    s[threadIdx.x] = (i < NNODES) ? deg[i] : 0;
    __syncthreads();
    for (int off = 512; off > 0; off >>= 1) {
        if (threadIdx.x < off) s[threadIdx.x] += s[threadIdx.x + off];
        __syncthreads();
    }
    if (threadIdx.x == 0) csum[blockIdx.x] = s[0];
}

__global__ void chunk_base_kernel(const int* __restrict__ csum, int* __restrict__ cbase,
                                  int* __restrict__ offs, int nchunks)
{
    int run = 0;
    for (int i = 0; i < nchunks; ++i) { cbase[i] = run; run += csum[i]; }
    offs[NNODES] = run;
}

__global__ __launch_bounds__(1024) void scan_kernel(const int* __restrict__ deg,
    const int* __restrict__ cbase, int* __restrict__ offs, int* __restrict__ cursor)
{
    __shared__ int s[1024];
    int i = blockIdx.x * 1024 + threadIdx.x;
    int v = (i < NNODES) ? deg[i] : 0;
    s[threadIdx.x] = v;
    __syncthreads();
    for (int off = 1; off < 1024; off <<= 1) {
        int t = (threadIdx.x >= off) ? s[threadIdx.x - off] : 0;
        __syncthreads();
        s[threadIdx.x] += t;
        __syncthreads();
    }
    if (i < NNODES) {
        int excl = cbase[blockIdx.x] + s[threadIdx.x] - v;  // exclusive
        offs[i] = excl;
        cursor[i] = excl;
    }
}

__global__ __launch_bounds__(256) void scatter_kernel(const int* __restrict__ src,
    const int* __restrict__ dst, const float* __restrict__ w,
    int* __restrict__ cursor, int2* __restrict__ srcw)
{
    int e = blockIdx.x * 256 + threadIdx.x;
    if (e < NEDGES) {
        int d = dst[e];
        int pos = atomicAdd(&cursor[d], 1);
        srcw[pos] = make_int2(src[e], __float_as_int(w[e]));
    }
}

// One wave per node: CSR gather SpMM -> z -> fused z@W[l] (LDS) -> blend + relu.
__global__ __launch_bounds__(256) void spmm_layer_kernel(const float* __restrict__ h_in,
    const float* __restrict__ x0, float* __restrict__ h_out,
    const int* __restrict__ offs, const int2* __restrict__ srcw,
    const float* __restrict__ Wg, float beta)
{
    __shared__ float Wl[HID * HID];   // 16 KB
    __shared__ float zs[4][HID];
    {
        const float4* wg4 = (const float4*)Wg;
        float4* wl4 = (float4*)Wl;
#pragma unroll
        for (int i = 0; i < 4; ++i)
            wl4[threadIdx.x + 256 * i] = wg4[threadIdx.x + 256 * i];
    }
    __syncthreads();
    const int m = threadIdx.x >> 6, lane = threadIdx.x & 63;
    const int n = blockIdx.x * 4 + m;
    const int e0 = offs[n], e1 = offs[n + 1];
    float acc = 0.f;
    int e = e0;
    for (; e + 1 < e1; e += 2) {        // unroll 2 for outstanding gathers
        int2 a = srcw[e];
        int2 c = srcw[e + 1];
        acc = fmaf(__int_as_float(a.y), h_in[(long)a.x * HID + lane], acc);
        acc = fmaf(__int_as_float(c.y), h_in[(long)c.x * HID + lane], acc);
    }
    if (e < e1) {
        int2 a = srcw[e];
        acc = fmaf(__int_as_float(a.y), h_in[(long)a.x * HID + lane], acc);
    }
    const float z = 0.9f * acc + 0.1f * x0[(long)n * HID + lane];
    zs[m][lane] = z;                    // wave-private row; no block sync needed
    float mm = 0.f;
    const float4* zrow = (const float4*)zs[m];
#pragma unroll
    for (int k4 = 0; k4 < 16; ++k4) {
        float4 zv = zrow[k4];           // LDS broadcast
        const int k = k4 * 4;
        mm = fmaf(zv.x, Wl[(k + 0) * HID + lane], mm);
        mm = fmaf(zv.y, Wl[(k + 1) * HID + lane], mm);
        mm = fmaf(zv.z, Wl[(k + 2) * HID + lane], mm);
        mm = fmaf(zv.w, Wl[(k + 3) * HID + lane], mm);
    }
    h_out[(long)n * HID + lane] = fmaxf((1.f - beta) * z + beta * mm, 0.f);
}

// out = log_softmax(h @ W1 + b1); one wave per node, lanes 0..39 = classes.
__global__ __launch_bounds__(256) void final_kernel(const float* __restrict__ h,
    const float* __restrict__ w1, const float* __restrict__ b1, float* __restrict__ out)
{
    const int m = threadIdx.x >> 6, j = threadIdx.x & 63;
    const long n = (long)blockIdx.x * 4 + m;
    const int jj = (j < NCLS) ? j : NCLS - 1;
    const float4* hrow = (const float4*)(h + n * HID);
    float acc = b1[jj];
#pragma unroll
    for (int k4 = 0; k4 < 16; ++k4) {
        float4 hv = hrow[k4];
        const int k = k4 * 4;
        acc = fmaf(hv.x, w1[(k + 0) * NCLS + jj], acc);
        acc = fmaf(hv.y, w1[(k + 1) * NCLS + jj], acc);
        acc = fmaf(hv.z, w1[(k + 2) * NCLS + jj], acc);
        acc = fmaf(hv.w, w1[(k + 3) * NCLS + jj], acc);
    }
    float lg = (j < NCLS) ? acc : -INFINITY;
    float mx = lg;
#pragma unroll
    for (int o = 32; o > 0; o >>= 1) mx = fmaxf(mx, __shfl_xor(mx, o, 64));
    float ex = (j < NCLS) ? expf(acc - mx) : 0.f;
    float sm = ex;
#pragma unroll
    for (int o = 32; o > 0; o >>= 1) sm += __shfl_xor(sm, o, 64);
    if (j < NCLS) out[n * NCLS + j] = acc - mx - logf(sm);
}

extern "C" void kernel_launch(void* const* d_in, const int* in_sizes, int n_in,
                              void* d_out, int out_size, void* d_ws, size_t ws_size,
                              hipStream_t stream)
{
    const float* x    = (const float*)d_in[0];
    const int*   esrc = (const int*)d_in[1];
    const int*   edst = (const int*)d_in[2];
    const float* ew   = (const float*)d_in[3];
    const float* l0w  = (const float*)d_in[4];
    const float* l0b  = (const float*)d_in[5];
    const float* cw   = (const float*)d_in[6];
    const float* l1w  = (const float*)d_in[7];
    const float* l1b  = (const float*)d_in[8];
    float* out = (float*)d_out;

    // workspace layout (~103 MB total)
    char* p = (char*)d_ws;
    float* h0   = (float*)p; p += (size_t)NNODES * HID * 4;
    float* hA   = (float*)p; p += (size_t)NNODES * HID * 4;
    float* hB   = (float*)p; p += (size_t)NNODES * HID * 4;
    int2*  srcw = (int2*)p;  p += (size_t)NEDGES * 8;
    int* offs   = (int*)p;   p += (size_t)(NNODES + 1) * 4;
    int* cursor = (int*)p;   p += (size_t)NNODES * 4;
    int* deg    = (int*)p;   p += (size_t)NNODES * 4;
    int* csum   = (int*)p;   p += 512;
    int* cbase  = (int*)p;   p += 512;

    const int nchunks = (NNODES + 1023) / 1024;   // 98

    hipMemsetAsync(deg, 0, NNODES * sizeof(int), stream);
    lin0_kernel<<<NNODES / 4, 256, 0, stream>>>(x, l0w, l0b, h0);
    count_kernel<<<(NEDGES + 255) / 256, 256, 0, stream>>>(edst, deg);
    chunk_sum_kernel<<<nchunks, 1024, 0, stream>>>(deg, csum);
    chunk_base_kernel<<<1, 1, 0, stream>>>(csum, cbase, offs, nchunks);
    scan_kernel<<<nchunks, 1024, 0, stream>>>(deg, cbase, offs, cursor);
    scatter_kernel<<<(NEDGES + 255) / 256, 256, 0, stream>>>(esrc, edst, ew, cursor, srcw);

    const float* hin = h0;
    float* bufs[2] = { hA, hB };
    for (int l = 0; l < NLAYERS; ++l) {
        float beta = (float)log(0.5 / (double)(l + 1) + 1.0);
        float* hout = bufs[l & 1];
        spmm_layer_kernel<<<NNODES / 4, 256, 0, stream>>>(
            hin, h0, hout, offs, srcw, cw + (size_t)l * HID * HID, beta);
        hin = hout;
    }
    final_kernel<<<NNODES / 4, 256, 0, stream>>>(hin, l1w, l1b, out);
}

// Round 2
// 2148.859 us; speedup vs baseline: 1.5738x; 1.5738x over previous
//
#include <hip/hip_runtime.h>
#include <math.h>

#define NNODES 100000
#define NEDGES 3200000
#define NFEAT  500
#define HID    64
#define NCLS   40
#define NLAYERS 8
#define KC     50      // lin0 k-chunk
#define NPB    8       // spmm nodes per block

static __device__ __forceinline__ float rdlane(float v, int l) {
    return __int_as_float(__builtin_amdgcn_readlane(__float_as_int(v), l));
}

// ---------------- lin0: h0 = relu(x @ W + b), tiled GEMM ----------------
// tile: 128 rows x 64 cols, 256 threads, each thread 8 rows x 4 cols.
__global__ __launch_bounds__(256) void lin0_kernel(const float* __restrict__ x,
    const float* __restrict__ w, const float* __restrict__ b, float* __restrict__ h0)
{
    __shared__ float xs[KC][132];   // transposed x tile: xs[k][m], pad 132 (bank rotate 4)
    __shared__ float ws[KC][64];    // ws[k][j]
    const int tid = threadIdx.x;
    const int m0 = blockIdx.x * 128;
    const int ty = tid >> 4, tx = tid & 15;      // ty: 16 row groups of 8, tx: 16 col groups of 4
    float acc[8][4];
#pragma unroll
    for (int r = 0; r < 8; ++r)
#pragma unroll
        for (int c = 0; c < 4; ++c) acc[r][c] = 0.f;

    for (int k0 = 0; k0 < NFEAT; k0 += KC) {
        // stage x chunk (transpose): 128 rows x 50 cols as float2 (200B chunks are 8B-aligned)
        for (int i = tid; i < 128 * 25; i += 256) {
            int m = i / 25, f2 = i % 25;
            int gm = m0 + m; gm = gm < NNODES ? gm : NNODES - 1;
            float2 v = *(const float2*)(x + (size_t)gm * NFEAT + k0 + f2 * 2);
            int k = f2 * 2;
            xs[k][m] = v.x; xs[k + 1][m] = v.y;
        }
        // stage w chunk: contiguous 50*64 floats = 800 float4
        for (int i = tid; i < 800; i += 256)
            ((float4*)ws)[i] = ((const float4*)(w + (size_t)k0 * HID))[i];
        __syncthreads();
#pragma unroll 2
        for (int k = 0; k < KC; ++k) {
            float4 xa = *(const float4*)&xs[k][ty * 8];
            float4 xb = *(const float4*)&xs[k][ty * 8 + 4];
            float4 wv = *(const float4*)&ws[k][tx * 4];
            const float xr[8] = { xa.x, xa.y, xa.z, xa.w, xb.x, xb.y, xb.z, xb.w };
#pragma unroll
            for (int r = 0; r < 8; ++r) {
                acc[r][0] = fmaf(xr[r], wv.x, acc[r][0]);
                acc[r][1] = fmaf(xr[r], wv.y, acc[r][1]);
                acc[r][2] = fmaf(xr[r], wv.z, acc[r][2]);
                acc[r][3] = fmaf(xr[r], wv.w, acc[r][3]);
            }
        }
        __syncthreads();
    }
    const float4 bv = *(const float4*)(b + tx * 4);
#pragma unroll
    for (int r = 0; r < 8; ++r) {
        int gm = m0 + ty * 8 + r;
        if (gm < NNODES) {
            float4 o;
            o.x = fmaxf(acc[r][0] + bv.x, 0.f);
            o.y = fmaxf(acc[r][1] + bv.y, 0.f);
            o.z = fmaxf(acc[r][2] + bv.z, 0.f);
            o.w = fmaxf(acc[r][3] + bv.w, 0.f);
            *(float4*)(h0 + (size_t)gm * HID + tx * 4) = o;
        }
    }
}

// ---------------- CSR build (dst-sorted, degree padded to multiple of 4) --------
__global__ __launch_bounds__(256) void count_kernel(const int* __restrict__ dst,
                                                    int* __restrict__ deg)
{
    int e = blockIdx.x * 256 + threadIdx.x;
    if (e < NEDGES) atomicAdd(&deg[dst[e]], 1);
}

__global__ __launch_bounds__(1024) void chunk_sum_kernel(const int* __restrict__ deg,
                                                         int* __restrict__ csum)
{
    __shared__ int s[1024];
    int i = blockIdx.x * 1024 + threadIdx.x;
    s[threadIdx.x] = (i < NNODES) ? ((deg[i] + 3) & ~3) : 0;
    __syncthreads();
    for (int off = 512; off > 0; off >>= 1) {
        if (threadIdx.x < off) s[threadIdx.x] += s[threadIdx.x + off];
        __syncthreads();
    }
    if (threadIdx.x == 0) csum[blockIdx.x] = s[0];
}

__global__ void chunk_base_kernel(const int* __restrict__ csum, int* __restrict__ cbase,
                                  int* __restrict__ offs, int nchunks)
{
    int run = 0;
    for (int i = 0; i < nchunks; ++i) { cbase[i] = run; run += csum[i]; }
    offs[NNODES] = run;
}

__global__ __launch_bounds__(1024) void scan_kernel(const int* __restrict__ deg,
    const int* __restrict__ cbase, int* __restrict__ offs, int* __restrict__ cursor)
{
    __shared__ int s[1024];
    int i = blockIdx.x * 1024 + threadIdx.x;
    int v = (i < NNODES) ? ((deg[i] + 3) & ~3) : 0;
    s[threadIdx.x] = v;
    __syncthreads();
    for (int off = 1; off < 1024; off <<= 1) {
        int t = (threadIdx.x >= off) ? s[threadIdx.x - off] : 0;
        __syncthreads();
        s[threadIdx.x] += t;
        __syncthreads();
    }
    if (i < NNODES) {
        int excl = cbase[blockIdx.x] + s[threadIdx.x] - v;
        offs[i] = excl;
        cursor[i] = excl;
    }
}

__global__ __launch_bounds__(256) void scatter_kernel(const int* __restrict__ src,
    const int* __restrict__ dst, const float* __restrict__ w,
    int* __restrict__ cursor, int2* __restrict__ srcw)
{
    int e = blockIdx.x * 256 + threadIdx.x;
    if (e < NEDGES) {
        int d = dst[e];
        int pos = atomicAdd(&cursor[d], 1);
        srcw[pos] = make_int2(src[e], __float_as_int(w[e]));
    }
}

__global__ __launch_bounds__(256) void pad_kernel(const int* __restrict__ offs,
    const int* __restrict__ deg, int2* __restrict__ srcw)
{
    int n = blockIdx.x * 256 + threadIdx.x;
    if (n < NNODES) {
        int e = offs[n] + deg[n], e1 = offs[n + 1];
        for (; e < e1; ++e) srcw[e] = make_int2(0, 0);
    }
}

// ---------------- fused SpMM + blend + dense + relu layer ----------------
// 8 nodes/block, wave m handles nodes (blk*8+m) and (blk*8+m+4); lane = feature.
__global__ __launch_bounds__(256) void spmm_layer_kernel(const float* __restrict__ h_in,
    const float* __restrict__ x0, float* __restrict__ h_out,
    const int* __restrict__ offs, const int2* __restrict__ srcw,
    const float* __restrict__ Wg, float beta)
{
    __shared__ float WlT[HID][HID];   // WlT[j][k] = Wg[k][j], 16 KB
    for (int i = threadIdx.x; i < 1024; i += 256) {
        float4 v = ((const float4*)Wg)[i];
        int k = i >> 4, j = (i & 15) * 4;
        WlT[j + 0][k] = v.x; WlT[j + 1][k] = v.y;
        WlT[j + 2][k] = v.z; WlT[j + 3][k] = v.w;
    }
    __syncthreads();
    const int m = threadIdx.x >> 6, lane = threadIdx.x & 63;
    const int nA = blockIdx.x * NPB + m;
    const int nB = nA + 4;
    const int eA0 = offs[nA], eA1 = offs[nA + 1];
    const int eB0 = offs[nB], eB1 = offs[nB + 1];
    float accA = 0.f, accB = 0.f;
#pragma unroll 2
    for (int e = eA0; e < eA1; e += 4) {
        int4 p = *(const int4*)(srcw + e);
        int4 q = *(const int4*)(srcw + e + 2);
        accA = fmaf(__int_as_float(p.y), h_in[(size_t)p.x * HID + lane], accA);
        accA = fmaf(__int_as_float(p.w), h_in[(size_t)p.z * HID + lane], accA);
        accA = fmaf(__int_as_float(q.y), h_in[(size_t)q.x * HID + lane], accA);
        accA = fmaf(__int_as_float(q.w), h_in[(size_t)q.z * HID + lane], accA);
    }
#pragma unroll 2
    for (int e = eB0; e < eB1; e += 4) {
        int4 p = *(const int4*)(srcw + e);
        int4 q = *(const int4*)(srcw + e + 2);
        accB = fmaf(__int_as_float(p.y), h_in[(size_t)p.x * HID + lane], accB);
        accB = fmaf(__int_as_float(p.w), h_in[(size_t)p.z * HID + lane], accB);
        accB = fmaf(__int_as_float(q.y), h_in[(size_t)q.x * HID + lane], accB);
        accB = fmaf(__int_as_float(q.w), h_in[(size_t)q.z * HID + lane], accB);
    }
    const float zA = 0.9f * accA + 0.1f * x0[(size_t)nA * HID + lane];
    const float zB = 0.9f * accB + 0.1f * x0[(size_t)nB * HID + lane];
    // mm[lane] = sum_k z[k] * W[k][lane]; W row for this lane via b128, z via readlane.
    float mA0 = 0.f, mA1 = 0.f, mB0 = 0.f, mB1 = 0.f;
    const float4* wrow = (const float4*)WlT[lane];
#pragma unroll 4
    for (int k4 = 0; k4 < 16; ++k4) {
        float4 wv = wrow[k4];
        const int k = k4 * 4;
        mA0 = fmaf(rdlane(zA, k + 0), wv.x, mA0);
        mA1 = fmaf(rdlane(zA, k + 1), wv.y, mA1);
        mA0 = fmaf(rdlane(zA, k + 2), wv.z, mA0);
        mA1 = fmaf(rdlane(zA, k + 3), wv.w, mA1);
        mB0 = fmaf(rdlane(zB, k + 0), wv.x, mB0);
        mB1 = fmaf(rdlane(zB, k + 1), wv.y, mB1);
        mB0 = fmaf(rdlane(zB, k + 2), wv.z, mB0);
        mB1 = fmaf(rdlane(zB, k + 3), wv.w, mB1);
    }
    const float ob = 1.f - beta;
    h_out[(size_t)nA * HID + lane] = fmaxf(ob * zA + beta * (mA0 + mA1), 0.f);
    h_out[(size_t)nB * HID + lane] = fmaxf(ob * zB + beta * (mB0 + mB1), 0.f);
}

// ---------------- final: log_softmax(h @ W1 + b1) ----------------
__global__ __launch_bounds__(256) void final_kernel(const float* __restrict__ h,
    const float* __restrict__ w1, const float* __restrict__ b1, float* __restrict__ out)
{
    const int m = threadIdx.x >> 6, j = threadIdx.x & 63;
    const long n = (long)blockIdx.x * 4 + m;
    const int jj = (j < NCLS) ? j : NCLS - 1;
    const float4* hrow = (const float4*)(h + n * HID);
    float acc = b1[jj];
#pragma unroll
    for (int k4 = 0; k4 < 16; ++k4) {
        float4 hv = hrow[k4];
        const int k = k4 * 4;
        acc = fmaf(hv.x, w1[(k + 0) * NCLS + jj], acc);
        acc = fmaf(hv.y, w1[(k + 1) * NCLS + jj], acc);
        acc = fmaf(hv.z, w1[(k + 2) * NCLS + jj], acc);
        acc = fmaf(hv.w, w1[(k + 3) * NCLS + jj], acc);
    }
    float lg = (j < NCLS) ? acc : -INFINITY;
    float mx = lg;
#pragma unroll
    for (int o = 32; o > 0; o >>= 1) mx = fmaxf(mx, __shfl_xor(mx, o, 64));
    float ex = (j < NCLS) ? expf(acc - mx) : 0.f;
    float sm = ex;
#pragma unroll
    for (int o = 32; o > 0; o >>= 1) sm += __shfl_xor(sm, o, 64);
    if (j < NCLS) out[n * NCLS + j] = acc - mx - logf(sm);
}

extern "C" void kernel_launch(void* const* d_in, const int* in_sizes, int n_in,
                              void* d_out, int out_size, void* d_ws, size_t ws_size,
                              hipStream_t stream)
{
    const float* x    = (const float*)d_in[0];
    const int*   esrc = (const int*)d_in[1];
    const int*   edst = (const int*)d_in[2];
    const float* ew   = (const float*)d_in[3];
    const float* l0w  = (const float*)d_in[4];
    const float* l0b  = (const float*)d_in[5];
    const float* cw   = (const float*)d_in[6];
    const float* l1w  = (const float*)d_in[7];
    const float* l1b  = (const float*)d_in[8];
    float* out = (float*)d_out;

    char* p = (char*)d_ws;
    float* h0   = (float*)p; p += (size_t)NNODES * HID * 4;
    float* hA   = (float*)p; p += (size_t)NNODES * HID * 4;
    float* hB   = (float*)p; p += (size_t)NNODES * HID * 4;
    int2*  srcw = (int2*)p;  p += ((size_t)NEDGES + 4 * NNODES) * 8;  // padded CSR
    int* offs   = (int*)p;   p += (size_t)(NNODES + 1) * 4;
    int* cursor = (int*)p;   p += (size_t)NNODES * 4;
    int* deg    = (int*)p;   p += (size_t)NNODES * 4;
    int* csum   = (int*)p;   p += 512;
    int* cbase  = (int*)p;   p += 512;

    const int nchunks = (NNODES + 1023) / 1024;   // 98

    hipMemsetAsync(deg, 0, NNODES * sizeof(int), stream);
    lin0_kernel<<<(NNODES + 127) / 128, 256, 0, stream>>>(x, l0w, l0b, h0);
    count_kernel<<<(NEDGES + 255) / 256, 256, 0, stream>>>(edst, deg);
    chunk_sum_kernel<<<nchunks, 1024, 0, stream>>>(deg, csum);
    chunk_base_kernel<<<1, 1, 0, stream>>>(csum, cbase, offs, nchunks);
    scan_kernel<<<nchunks, 1024, 0, stream>>>(deg, cbase, offs, cursor);
    scatter_kernel<<<(NEDGES + 255) / 256, 256, 0, stream>>>(esrc, edst, ew, cursor, srcw);
    pad_kernel<<<(NNODES + 255) / 256, 256, 0, stream>>>(offs, deg, srcw);

    const float* hin = h0;
    float* bufs[2] = { hA, hB };
    for (int l = 0; l < NLAYERS; ++l) {
        float beta = (float)log(0.5 / (double)(l + 1) + 1.0);
        float* hout = bufs[l & 1];
        spmm_layer_kernel<<<NNODES / NPB, 256, 0, stream>>>(
            hin, h0, hout, offs, srcw, cw + (size_t)l * HID * HID, beta);
        hin = hout;
    }
    final_kernel<<<NNODES / 4, 256, 0, stream>>>(hin, l1w, l1b, out);
}

// Round 3
// 1954.347 us; speedup vs baseline: 1.7304x; 1.0995x over previous
//
#include <hip/hip_runtime.h>
#include <math.h>

#define NNODES 100000
#define NEDGES 3200000
#define NFEAT  500
#define HID    64
#define NCLS   40
#define NLAYERS 8
#define KC     50      // lin0 k-chunk
#define NPB    8       // spmm nodes per block
#define NODES_PER_PART 12500   // NNODES / 8 (XCD-partitioned scatter)

static __device__ __forceinline__ float rdlane(float v, int l) {
    return __int_as_float(__builtin_amdgcn_readlane(__float_as_int(v), l));
}
static __device__ __forceinline__ float b2f(unsigned short u) {
    return __uint_as_float(((unsigned)u) << 16);
}
static __device__ __forceinline__ unsigned short f2b(float f) {
    unsigned u = __float_as_uint(f);
    return (unsigned short)((u + 0x7FFFu + ((u >> 16) & 1u)) >> 16);  // RNE
}

// ---------------- lin0: h0 = relu(x @ W + b), tiled GEMM, bf16 out ----------------
__global__ __launch_bounds__(256) void lin0_kernel(const float* __restrict__ x,
    const float* __restrict__ w, const float* __restrict__ b,
    unsigned short* __restrict__ h0)
{
    __shared__ float xs[KC][132];   // transposed x tile: xs[k][m], pad->132
    __shared__ float ws[KC][64];    // ws[k][j]
    const int tid = threadIdx.x;
    const int m0 = blockIdx.x * 128;
    const int ty = tid >> 4, tx = tid & 15;
    float acc[8][4];
#pragma unroll
    for (int r = 0; r < 8; ++r)
#pragma unroll
        for (int c = 0; c < 4; ++c) acc[r][c] = 0.f;

    for (int k0 = 0; k0 < NFEAT; k0 += KC) {
        for (int i = tid; i < 128 * 25; i += 256) {
            int m = i / 25, f2 = i % 25;
            int gm = m0 + m; gm = gm < NNODES ? gm : NNODES - 1;
            float2 v = *(const float2*)(x + (size_t)gm * NFEAT + k0 + f2 * 2);
            int k = f2 * 2;
            xs[k][m] = v.x; xs[k + 1][m] = v.y;
        }
        for (int i = tid; i < 800; i += 256)
            ((float4*)ws)[i] = ((const float4*)(w + (size_t)k0 * HID))[i];
        __syncthreads();
#pragma unroll 2
        for (int k = 0; k < KC; ++k) {
            float4 xa = *(const float4*)&xs[k][ty * 8];
            float4 xb = *(const float4*)&xs[k][ty * 8 + 4];
            float4 wv = *(const float4*)&ws[k][tx * 4];
            const float xr[8] = { xa.x, xa.y, xa.z, xa.w, xb.x, xb.y, xb.z, xb.w };
#pragma unroll
            for (int r = 0; r < 8; ++r) {
                acc[r][0] = fmaf(xr[r], wv.x, acc[r][0]);
                acc[r][1] = fmaf(xr[r], wv.y, acc[r][1]);
                acc[r][2] = fmaf(xr[r], wv.z, acc[r][2]);
                acc[r][3] = fmaf(xr[r], wv.w, acc[r][3]);
            }
        }
        __syncthreads();
    }
    const float4 bv = *(const float4*)(b + tx * 4);
#pragma unroll
    for (int r = 0; r < 8; ++r) {
        int gm = m0 + ty * 8 + r;
        if (gm < NNODES) {
            ushort4 o;
            o.x = f2b(fmaxf(acc[r][0] + bv.x, 0.f));
            o.y = f2b(fmaxf(acc[r][1] + bv.y, 0.f));
            o.z = f2b(fmaxf(acc[r][2] + bv.z, 0.f));
            o.w = f2b(fmaxf(acc[r][3] + bv.w, 0.f));
            *(ushort4*)(h0 + (size_t)gm * HID + tx * 4) = o;
        }
    }
}

// ---------------- CSR build (dst-sorted, degree padded to multiple of 4) --------
__global__ __launch_bounds__(256) void count_kernel(const int* __restrict__ dst,
                                                    int* __restrict__ deg)
{
    int e = blockIdx.x * 256 + threadIdx.x;
    if (e < NEDGES) atomicAdd(&deg[dst[e]], 1);
}

__global__ __launch_bounds__(1024) void chunk_sum_kernel(const int* __restrict__ deg,
                                                         int* __restrict__ csum)
{
    __shared__ int s[1024];
    int i = blockIdx.x * 1024 + threadIdx.x;
    s[threadIdx.x] = (i < NNODES) ? ((deg[i] + 3) & ~3) : 0;
    __syncthreads();
    for (int off = 512; off > 0; off >>= 1) {
        if (threadIdx.x < off) s[threadIdx.x] += s[threadIdx.x + off];
        __syncthreads();
    }
    if (threadIdx.x == 0) csum[blockIdx.x] = s[0];
}

__global__ void chunk_base_kernel(const int* __restrict__ csum, int* __restrict__ cbase,
                                  int* __restrict__ offs, int nchunks)
{
    int run = 0;
    for (int i = 0; i < nchunks; ++i) { cbase[i] = run; run += csum[i]; }
    offs[NNODES] = run;
}

__global__ __launch_bounds__(1024) void scan_kernel(const int* __restrict__ deg,
    const int* __restrict__ cbase, int* __restrict__ offs, int* __restrict__ cursor)
{
    __shared__ int s[1024];
    int i = blockIdx.x * 1024 + threadIdx.x;
    int v = (i < NNODES) ? ((deg[i] + 3) & ~3) : 0;
    s[threadIdx.x] = v;
    __syncthreads();
    for (int off = 1; off < 1024; off <<= 1) {
        int t = (threadIdx.x >= off) ? s[threadIdx.x - off] : 0;
        __syncthreads();
        s[threadIdx.x] += t;
        __syncthreads();
    }
    if (i < NNODES) {
        int excl = cbase[blockIdx.x] + s[threadIdx.x] - v;
        offs[i] = excl;
        cursor[i] = excl;
    }
}

// XCD-partitioned scatter: block (slice = bid>>3, part = bid&7) writes only
// edges with dst in part's 12.5k-node range -> each 3.2MB CSR region is
// written by one XCD (round-robin dispatch) -> partial lines merge in its L2.
__global__ __launch_bounds__(256) void scatter_kernel(const int* __restrict__ src,
    const int* __restrict__ dst, const float* __restrict__ w,
    int* __restrict__ cursor, int2* __restrict__ srcw)
{
    const int part = blockIdx.x & 7;
    const int e = (blockIdx.x >> 3) * 256 + threadIdx.x;   // grid covers E exactly
    const int d = dst[e];
    const int s = src[e];
    const float wt = w[e];
    if (d / NODES_PER_PART == part) {
        int pos = atomicAdd(&cursor[d], 1);
        srcw[pos] = make_int2(s, __float_as_int(wt));
    }
}

__global__ __launch_bounds__(256) void pad_kernel(const int* __restrict__ offs,
    const int* __restrict__ deg, int2* __restrict__ srcw)
{
    int n = blockIdx.x * 256 + threadIdx.x;
    if (n < NNODES) {
        int e = offs[n] + deg[n], e1 = offs[n + 1];
        for (; e < e1; ++e) srcw[e] = make_int2(0, 0);
    }
}

// ---------------- fused SpMM + blend + dense + relu layer (bf16 h) ----------------
__global__ __launch_bounds__(256) void spmm_layer_kernel(
    const unsigned short* __restrict__ h_in, const unsigned short* __restrict__ x0,
    unsigned short* __restrict__ h_out, const int* __restrict__ offs,
    const int2* __restrict__ srcw, const float* __restrict__ Wg, float beta)
{
    __shared__ float WlT[HID][HID];   // WlT[j][k] = Wg[k][j]
    for (int i = threadIdx.x; i < 1024; i += 256) {
        float4 v = ((const float4*)Wg)[i];
        int k = i >> 4, j = (i & 15) * 4;
        WlT[j + 0][k] = v.x; WlT[j + 1][k] = v.y;
        WlT[j + 2][k] = v.z; WlT[j + 3][k] = v.w;
    }
    __syncthreads();
    const int m = threadIdx.x >> 6, lane = threadIdx.x & 63;
    const int nA = blockIdx.x * NPB + m;
    const int nB = nA + 4;
    const int eA0 = offs[nA], eA1 = offs[nA + 1];
    const int eB0 = offs[nB], eB1 = offs[nB + 1];
    float accA = 0.f, accB = 0.f;
#pragma unroll 2
    for (int e = eA0; e < eA1; e += 4) {
        int4 p = *(const int4*)(srcw + e);
        int4 q = *(const int4*)(srcw + e + 2);
        accA = fmaf(__int_as_float(p.y), b2f(h_in[(size_t)p.x * HID + lane]), accA);
        accA = fmaf(__int_as_float(p.w), b2f(h_in[(size_t)p.z * HID + lane]), accA);
        accA = fmaf(__int_as_float(q.y), b2f(h_in[(size_t)q.x * HID + lane]), accA);
        accA = fmaf(__int_as_float(q.w), b2f(h_in[(size_t)q.z * HID + lane]), accA);
    }
#pragma unroll 2
    for (int e = eB0; e < eB1; e += 4) {
        int4 p = *(const int4*)(srcw + e);
        int4 q = *(const int4*)(srcw + e + 2);
        accB = fmaf(__int_as_float(p.y), b2f(h_in[(size_t)p.x * HID + lane]), accB);
        accB = fmaf(__int_as_float(p.w), b2f(h_in[(size_t)p.z * HID + lane]), accB);
        accB = fmaf(__int_as_float(q.y), b2f(h_in[(size_t)q.x * HID + lane]), accB);
        accB = fmaf(__int_as_float(q.w), b2f(h_in[(size_t)q.z * HID + lane]), accB);
    }
    const float zA = 0.9f * accA + 0.1f * b2f(x0[(size_t)nA * HID + lane]);
    const float zB = 0.9f * accB + 0.1f * b2f(x0[(size_t)nB * HID + lane]);
    float mA0 = 0.f, mA1 = 0.f, mB0 = 0.f, mB1 = 0.f;
    const float4* wrow = (const float4*)WlT[lane];
#pragma unroll 4
    for (int k4 = 0; k4 < 16; ++k4) {
        float4 wv = wrow[k4];
        const int k = k4 * 4;
        mA0 = fmaf(rdlane(zA, k + 0), wv.x, mA0);
        mA1 = fmaf(rdlane(zA, k + 1), wv.y, mA1);
        mA0 = fmaf(rdlane(zA, k + 2), wv.z, mA0);
        mA1 = fmaf(rdlane(zA, k + 3), wv.w, mA1);
        mB0 = fmaf(rdlane(zB, k + 0), wv.x, mB0);
        mB1 = fmaf(rdlane(zB, k + 1), wv.y, mB1);
        mB0 = fmaf(rdlane(zB, k + 2), wv.z, mB0);
        mB1 = fmaf(rdlane(zB, k + 3), wv.w, mB1);
    }
    const float ob = 1.f - beta;
    h_out[(size_t)nA * HID + lane] = f2b(fmaxf(ob * zA + beta * (mA0 + mA1), 0.f));
    h_out[(size_t)nB * HID + lane] = f2b(fmaxf(ob * zB + beta * (mB0 + mB1), 0.f));
}

// ---------------- final: log_softmax(h @ W1 + b1) ----------------
__global__ __launch_bounds__(256) void final_kernel(const unsigned short* __restrict__ h,
    const float* __restrict__ w1, const float* __restrict__ b1, float* __restrict__ out)
{
    const int m = threadIdx.x >> 6, j = threadIdx.x & 63;
    const long n = (long)blockIdx.x * 4 + m;
    const int jj = (j < NCLS) ? j : NCLS - 1;
    const ushort4* hrow = (const ushort4*)(h + n * HID);
    float acc = b1[jj];
#pragma unroll
    for (int k4 = 0; k4 < 16; ++k4) {
        ushort4 hv = hrow[k4];
        const int k = k4 * 4;
        acc = fmaf(b2f(hv.x), w1[(k + 0) * NCLS + jj], acc);
        acc = fmaf(b2f(hv.y), w1[(k + 1) * NCLS + jj], acc);
        acc = fmaf(b2f(hv.z), w1[(k + 2) * NCLS + jj], acc);
        acc = fmaf(b2f(hv.w), w1[(k + 3) * NCLS + jj], acc);
    }
    float lg = (j < NCLS) ? acc : -INFINITY;
    float mx = lg;
#pragma unroll
    for (int o = 32; o > 0; o >>= 1) mx = fmaxf(mx, __shfl_xor(mx, o, 64));
    float ex = (j < NCLS) ? expf(acc - mx) : 0.f;
    float sm = ex;
#pragma unroll
    for (int o = 32; o > 0; o >>= 1) sm += __shfl_xor(sm, o, 64);
    if (j < NCLS) out[n * NCLS + j] = acc - mx - logf(sm);
}

extern "C" void kernel_launch(void* const* d_in, const int* in_sizes, int n_in,
                              void* d_out, int out_size, void* d_ws, size_t ws_size,
                              hipStream_t stream)
{
    const float* x    = (const float*)d_in[0];
    const int*   esrc = (const int*)d_in[1];
    const int*   edst = (const int*)d_in[2];
    const float* ew   = (const float*)d_in[3];
    const float* l0w  = (const float*)d_in[4];
    const float* l0b  = (const float*)d_in[5];
    const float* cw   = (const float*)d_in[6];
    const float* l1w  = (const float*)d_in[7];
    const float* l1b  = (const float*)d_in[8];
    float* out = (float*)d_out;

    char* p = (char*)d_ws;
    unsigned short* h0 = (unsigned short*)p; p += (size_t)NNODES * HID * 2;
    unsigned short* hA = (unsigned short*)p; p += (size_t)NNODES * HID * 2;
    unsigned short* hB = (unsigned short*)p; p += (size_t)NNODES * HID * 2;
    int2*  srcw = (int2*)p;  p += ((size_t)NEDGES + 4 * NNODES) * 8;  // padded CSR
    int* offs   = (int*)p;   p += (size_t)(NNODES + 1) * 4;
    int* cursor = (int*)p;   p += (size_t)NNODES * 4;
    int* deg    = (int*)p;   p += (size_t)NNODES * 4;
    int* csum   = (int*)p;   p += 512;
    int* cbase  = (int*)p;   p += 512;

    const int nchunks = (NNODES + 1023) / 1024;   // 98

    hipMemsetAsync(deg, 0, NNODES * sizeof(int), stream);
    lin0_kernel<<<(NNODES + 127) / 128, 256, 0, stream>>>(x, l0w, l0b, h0);
    count_kernel<<<(NEDGES + 255) / 256, 256, 0, stream>>>(edst, deg);
    chunk_sum_kernel<<<nchunks, 1024, 0, stream>>>(deg, csum);
    chunk_base_kernel<<<1, 1, 0, stream>>>(csum, cbase, offs, nchunks);
    scan_kernel<<<nchunks, 1024, 0, stream>>>(deg, cbase, offs, cursor);
    scatter_kernel<<<(NEDGES / 256) * 8, 256, 0, stream>>>(esrc, edst, ew, cursor, srcw);
    pad_kernel<<<(NNODES + 255) / 256, 256, 0, stream>>>(offs, deg, srcw);

    const unsigned short* hin = h0;
    unsigned short* bufs[2] = { hA, hB };
    for (int l = 0; l < NLAYERS; ++l) {
        float beta = (float)log(0.5 / (double)(l + 1) + 1.0);
        unsigned short* hout = bufs[l & 1];
        spmm_layer_kernel<<<NNODES / NPB, 256, 0, stream>>>(
            hin, h0, hout, offs, srcw, cw + (size_t)l * HID * HID, beta);
        hin = hout;
    }
    final_kernel<<<NNODES / 4, 256, 0, stream>>>(hin, l1w, l1b, out);
}

// Round 4
// 1332.649 us; speedup vs baseline: 2.5377x; 1.4665x over previous
//
#include <hip/hip_runtime.h>
#include <math.h>

#define NNODES 100000
#define NEDGES 3200000
#define NFEAT  500
#define HID    64
#define NCLS   40
#define NLAYERS 8
#define NPB    8       // spmm nodes per block
#define NODES_PER_PART 12500   // NNODES / 8 (XCD-partitioned build)

typedef __attribute__((ext_vector_type(8))) short short8;   // 8 bf16 (4 VGPRs)
typedef __attribute__((ext_vector_type(4))) float floatx4;  // MFMA acc

static __device__ __forceinline__ float b2f(unsigned short u) {
    return __uint_as_float(((unsigned)u) << 16);
}
static __device__ __forceinline__ unsigned short f2b(float f) {
    unsigned u = __float_as_uint(f);
    return (unsigned short)((u + 0x7FFFu + ((u >> 16) & 1u)) >> 16);  // RNE
}
static __device__ __forceinline__ ushort4 pk4(float4 v) {
    return make_ushort4(f2b(v.x), f2b(v.y), f2b(v.z), f2b(v.w));
}

// ---------------- lin0: h0 = relu(x @ W + b)  --  MFMA bf16 GEMM ----------------
// block: 256 thr / 4 waves, tile M=128 x N=64, K chunks of 32 (500 padded to 512).
__global__ __launch_bounds__(256) void lin0_kernel(const float* __restrict__ x,
    const float* __restrict__ w, const float* __restrict__ b,
    unsigned short* __restrict__ h0)
{
    __shared__ unsigned short as_[128][40];  // A tile bf16 [m][k], rows padded 32->40
    __shared__ unsigned short wt[64][40];    // W^T chunk bf16 [n][k]
    const int tid = threadIdx.x;
    const int wv = tid >> 6, lane = tid & 63;
    const int ln15 = lane & 15, q = lane >> 4;
    const int m0 = blockIdx.x * 128;

    floatx4 acc[2][4];
#pragma unroll
    for (int i = 0; i < 2; ++i)
#pragma unroll
        for (int t = 0; t < 4; ++t) acc[i][t] = (floatx4){0.f, 0.f, 0.f, 0.f};

    const int r_ = tid >> 1, hh = tid & 1;       // staging: row, 16-float half
    int gms = m0 + r_; if (gms >= NNODES) gms = NNODES - 1;
    const float* xrow = x + (size_t)gms * NFEAT;

    for (int c = 0; c < 16; ++c) {
        const int k0 = c * 32;
        // ---- stage A: 128 x 32 fp32 -> bf16 ----
        {
            float4 v0, v1, v2, v3;
            if (c < 15 || hh == 0) {
                const float4* p4 = (const float4*)(xrow + k0 + 16 * hh);
                v0 = p4[0]; v1 = p4[1]; v2 = p4[2]; v3 = p4[3];
            } else {  // tail: k 496..511, only 496..499 valid
                v0 = *(const float4*)(xrow + 496);
                v1 = make_float4(0, 0, 0, 0); v2 = v1; v3 = v1;
            }
            ushort4* dst4 = (ushort4*)&as_[r_][16 * hh];
            dst4[0] = pk4(v0); dst4[1] = pk4(v1); dst4[2] = pk4(v2); dst4[3] = pk4(v3);
        }
        // ---- stage W^T: 32 x 64 fp32 -> bf16 [n][k] ----
#pragma unroll
        for (int ii = 0; ii < 2; ++ii) {
            int i = tid + ii * 256;               // float4 index in chunk (512 total)
            int k = i >> 4, nb = (i & 15) * 4;
            float4 v = make_float4(0, 0, 0, 0);
            if (c < 15 || i < 320)                // k0+k < 500
                v = ((const float4*)(w + (size_t)k0 * HID))[i];
            wt[nb + 0][k] = f2b(v.x); wt[nb + 1][k] = f2b(v.y);
            wt[nb + 2][k] = f2b(v.z); wt[nb + 3][k] = f2b(v.w);
        }
        __syncthreads();
        // ---- frags + MFMA ----
        short8 af[2], bfr[4];
#pragma unroll
        for (int mt = 0; mt < 2; ++mt)
            af[mt] = *(const short8*)&as_[32 * wv + 16 * mt + ln15][8 * q];
#pragma unroll
        for (int t = 0; t < 4; ++t)
            bfr[t] = *(const short8*)&wt[16 * t + ln15][8 * q];
#pragma unroll
        for (int mt = 0; mt < 2; ++mt)
#pragma unroll
            for (int t = 0; t < 4; ++t)
                acc[mt][t] = __builtin_amdgcn_mfma_f32_16x16x32_bf16(
                    af[mt], bfr[t], acc[mt][t], 0, 0, 0);
        __syncthreads();
    }
    // ---- epilogue: C/D layout col=lane&15, row=q*4+reg ----
    float bv[4];
#pragma unroll
    for (int t = 0; t < 4; ++t) bv[t] = b[16 * t + ln15];
#pragma unroll
    for (int mt = 0; mt < 2; ++mt)
#pragma unroll
        for (int r = 0; r < 4; ++r) {
            int gm = m0 + 32 * wv + 16 * mt + q * 4 + r;
            if (gm < NNODES) {
#pragma unroll
                for (int t = 0; t < 4; ++t)
                    h0[(size_t)gm * HID + 16 * t + ln15] =
                        f2b(fmaxf(acc[mt][t][r] + bv[t], 0.f));
            }
        }
}

// ---------------- CSR build (dst-sorted, deg padded to mult of 4) --------
// XCD-partitioned: block (slice=bid>>3, part=bid&7) handles only dst in its
// 12.5k-node range -> atomics/writes stay in one XCD's L2.
__global__ __launch_bounds__(256) void count_kernel(const int* __restrict__ dst,
                                                    int* __restrict__ deg)
{
    const int part = blockIdx.x & 7;
    const int e = (blockIdx.x >> 3) * 256 + threadIdx.x;
    const int d = dst[e];
    if (d / NODES_PER_PART == part) atomicAdd(&deg[d], 1);
}

__global__ __launch_bounds__(1024) void chunk_sum_kernel(const int* __restrict__ deg,
                                                         int* __restrict__ csum)
{
    __shared__ int s[1024];
    int i = blockIdx.x * 1024 + threadIdx.x;
    s[threadIdx.x] = (i < NNODES) ? ((deg[i] + 3) & ~3) : 0;
    __syncthreads();
    for (int off = 512; off > 0; off >>= 1) {
        if (threadIdx.x < off) s[threadIdx.x] += s[threadIdx.x + off];
        __syncthreads();
    }
    if (threadIdx.x == 0) csum[blockIdx.x] = s[0];
}

__global__ void chunk_base_kernel(const int* __restrict__ csum, int* __restrict__ cbase,
                                  int* __restrict__ offs, int nchunks)
{
    int run = 0;
    for (int i = 0; i < nchunks; ++i) { cbase[i] = run; run += csum[i]; }
    offs[NNODES] = run;
}

__global__ __launch_bounds__(1024) void scan_kernel(const int* __restrict__ deg,
    const int* __restrict__ cbase, int* __restrict__ offs, int* __restrict__ cursor)
{
    __shared__ int s[1024];
    int i = blockIdx.x * 1024 + threadIdx.x;
    int v = (i < NNODES) ? ((deg[i] + 3) & ~3) : 0;
    s[threadIdx.x] = v;
    __syncthreads();
    for (int off = 1; off < 1024; off <<= 1) {
        int t = (threadIdx.x >= off) ? s[threadIdx.x - off] : 0;
        __syncthreads();
        s[threadIdx.x] += t;
        __syncthreads();
    }
    if (i < NNODES) {
        int excl = cbase[blockIdx.x] + s[threadIdx.x] - v;
        offs[i] = excl;
        cursor[i] = excl;
    }
}

__global__ __launch_bounds__(256) void scatter_kernel(const int* __restrict__ src,
    const int* __restrict__ dst, const float* __restrict__ w,
    int* __restrict__ cursor, int2* __restrict__ srcw)
{
    const int part = blockIdx.x & 7;
    const int e = (blockIdx.x >> 3) * 256 + threadIdx.x;
    const int d = dst[e];
    if (d / NODES_PER_PART == part) {
        int pos = atomicAdd(&cursor[d], 1);
        srcw[pos] = make_int2(src[e] * 128, __float_as_int(w[e]));  // byte offset
    }
}

__global__ __launch_bounds__(256) void pad_kernel(const int* __restrict__ offs,
    const int* __restrict__ deg, int2* __restrict__ srcw)
{
    int n = blockIdx.x * 256 + threadIdx.x;
    if (n < NNODES) {
        int e = offs[n] + deg[n], e1 = offs[n + 1];
        for (; e < e1; ++e) srcw[e] = make_int2(0, 0);
    }
}

// ---------------- fused SpMM + blend + dense + relu layer ----------------
// Gather: half-wave per node (lane 0-31 node A, 32-63 node B), ushort2/lane
//   -> one global load fetches two 128B rows. srcw.x is pre-scaled byte offset.
// Dense: WlT[64][68] (68-pad -> b128 reads bank-conflict-free), wave wv
//   handles local nodes 2wv, 2wv+1, lane = output feature.
__global__ __launch_bounds__(256) void spmm_layer_kernel(
    const unsigned short* __restrict__ h_in, const unsigned short* __restrict__ x0,
    unsigned short* __restrict__ h_out, const int* __restrict__ offs,
    const int2* __restrict__ srcw, const float* __restrict__ Wg, float beta)
{
    __shared__ float WlT[HID][68];   // WlT[j][k] = Wg[k][j]
    __shared__ float zs[NPB][HID];
    for (int i = threadIdx.x; i < 1024; i += 256) {
        float4 v = ((const float4*)Wg)[i];
        int k = i >> 4, j = (i & 15) * 4;
        WlT[j + 0][k] = v.x; WlT[j + 1][k] = v.y;
        WlT[j + 2][k] = v.z; WlT[j + 3][k] = v.w;
    }
    const int wv = threadIdx.x >> 6, lane = threadIdx.x & 63;
    const int half = lane >> 5, ln = lane & 31;
    const int nloc = wv + half * 4;
    const int n = blockIdx.x * NPB + nloc;
    int e = offs[n];
    const int e1 = offs[n + 1];
    const char* hb = (const char*)h_in;
    float a0 = 0.f, a1 = 0.f;
#pragma unroll 2
    for (; e < e1; e += 2) {        // deg padded to multiple of 4
        int2 p = srcw[e];
        int2 r = srcw[e + 1];
        unsigned v0 = *(const unsigned*)(hb + p.x + ln * 4);
        unsigned v1 = *(const unsigned*)(hb + r.x + ln * 4);
        float w0 = __int_as_float(p.y), w1 = __int_as_float(r.y);
        a0 = fmaf(w0, __uint_as_float(v0 << 16), a0);
        a1 = fmaf(w0, __uint_as_float(v0 & 0xffff0000u), a1);
        a0 = fmaf(w1, __uint_as_float(v1 << 16), a0);
        a1 = fmaf(w1, __uint_as_float(v1 & 0xffff0000u), a1);
    }
    unsigned xv = *(const unsigned*)((const char*)x0 + (size_t)n * 128 + ln * 4);
    zs[nloc][2 * ln]     = 0.9f * a0 + 0.1f * __uint_as_float(xv << 16);
    zs[nloc][2 * ln + 1] = 0.9f * a1 + 0.1f * __uint_as_float(xv & 0xffff0000u);
    __syncthreads();
    // dense phase
    const int j = lane;
    const int na = 2 * wv, nb = 2 * wv + 1;
    const float4* wrow = (const float4*)WlT[j];       // 272B rows, 16B aligned
    const float4* zap = (const float4*)zs[na];
    const float4* zbp = (const float4*)zs[nb];
    float mm0 = 0.f, mm1 = 0.f;
#pragma unroll
    for (int k4 = 0; k4 < 16; ++k4) {
        float4 wvv = wrow[k4];
        float4 za = zap[k4], zb = zbp[k4];
        mm0 = fmaf(za.x, wvv.x, mm0); mm1 = fmaf(zb.x, wvv.x, mm1);
        mm0 = fmaf(za.y, wvv.y, mm0); mm1 = fmaf(zb.y, wvv.y, mm1);
        mm0 = fmaf(za.z, wvv.z, mm0); mm1 = fmaf(zb.z, wvv.z, mm1);
        mm0 = fmaf(za.w, wvv.w, mm0); mm1 = fmaf(zb.w, wvv.w, mm1);
    }
    const float ob = 1.f - beta;
    const size_t base = (size_t)blockIdx.x * NPB;
    h_out[(base + na) * HID + j] = f2b(fmaxf(ob * zs[na][j] + beta * mm0, 0.f));
    h_out[(base + nb) * HID + j] = f2b(fmaxf(ob * zs[nb][j] + beta * mm1, 0.f));
}

// ---------------- final: log_softmax(h @ W1 + b1) ----------------
__global__ __launch_bounds__(256) void final_kernel(const unsigned short* __restrict__ h,
    const float* __restrict__ w1, const float* __restrict__ b1, float* __restrict__ out)
{
    const int m = threadIdx.x >> 6, j = threadIdx.x & 63;
    const long n = (long)blockIdx.x * 4 + m;
    const int jj = (j < NCLS) ? j : NCLS - 1;
    const ushort4* hrow = (const ushort4*)(h + n * HID);
    float acc = b1[jj];
#pragma unroll
    for (int k4 = 0; k4 < 16; ++k4) {
        ushort4 hv = hrow[k4];
        const int k = k4 * 4;
        acc = fmaf(b2f(hv.x), w1[(k + 0) * NCLS + jj], acc);
        acc = fmaf(b2f(hv.y), w1[(k + 1) * NCLS + jj], acc);
        acc = fmaf(b2f(hv.z), w1[(k + 2) * NCLS + jj], acc);
        acc = fmaf(b2f(hv.w), w1[(k + 3) * NCLS + jj], acc);
    }
    float lg = (j < NCLS) ? acc : -INFINITY;
    float mx = lg;
#pragma unroll
    for (int o = 32; o > 0; o >>= 1) mx = fmaxf(mx, __shfl_xor(mx, o, 64));
    float ex = (j < NCLS) ? expf(acc - mx) : 0.f;
    float sm = ex;
#pragma unroll
    for (int o = 32; o > 0; o >>= 1) sm += __shfl_xor(sm, o, 64);
    if (j < NCLS) out[n * NCLS + j] = acc - mx - logf(sm);
}

extern "C" void kernel_launch(void* const* d_in, const int* in_sizes, int n_in,
                              void* d_out, int out_size, void* d_ws, size_t ws_size,
                              hipStream_t stream)
{
    const float* x    = (const float*)d_in[0];
    const int*   esrc = (const int*)d_in[1];
    const int*   edst = (const int*)d_in[2];
    const float* ew   = (const float*)d_in[3];
    const float* l0w  = (const float*)d_in[4];
    const float* l0b  = (const float*)d_in[5];
    const float* cw   = (const float*)d_in[6];
    const float* l1w  = (const float*)d_in[7];
    const float* l1b  = (const float*)d_in[8];
    float* out = (float*)d_out;

    char* p = (char*)d_ws;
    unsigned short* h0 = (unsigned short*)p; p += (size_t)NNODES * HID * 2;
    unsigned short* hA = (unsigned short*)p; p += (size_t)NNODES * HID * 2;
    unsigned short* hB = (unsigned short*)p; p += (size_t)NNODES * HID * 2;
    int2*  srcw = (int2*)p;  p += ((size_t)NEDGES + 4 * NNODES) * 8;  // padded CSR
    int* offs   = (int*)p;   p += (size_t)(NNODES + 1) * 4;
    int* cursor = (int*)p;   p += (size_t)NNODES * 4;
    int* deg    = (int*)p;   p += (size_t)NNODES * 4;
    int* csum   = (int*)p;   p += 512;
    int* cbase  = (int*)p;   p += 512;

    const int nchunks = (NNODES + 1023) / 1024;   // 98

    hipMemsetAsync(deg, 0, NNODES * sizeof(int), stream);
    lin0_kernel<<<(NNODES + 127) / 128, 256, 0, stream>>>(x, l0w, l0b, h0);
    count_kernel<<<(NEDGES / 256) * 8, 256, 0, stream>>>(edst, deg);
    chunk_sum_kernel<<<nchunks, 1024, 0, stream>>>(deg, csum);
    chunk_base_kernel<<<1, 1, 0, stream>>>(csum, cbase, offs, nchunks);
    scan_kernel<<<nchunks, 1024, 0, stream>>>(deg, cbase, offs, cursor);
    scatter_kernel<<<(NEDGES / 256) * 8, 256, 0, stream>>>(esrc, edst, ew, cursor, srcw);
    pad_kernel<<<(NNODES + 255) / 256, 256, 0, stream>>>(offs, deg, srcw);

    const unsigned short* hin = h0;
    unsigned short* bufs[2] = { hA, hB };
    for (int l = 0; l < NLAYERS; ++l) {
        float beta = (float)log(0.5 / (double)(l + 1) + 1.0);
        unsigned short* hout = bufs[l & 1];
        spmm_layer_kernel<<<NNODES / NPB, 256, 0, stream>>>(
            hin, h0, hout, offs, srcw, cw + (size_t)l * HID * HID, beta);
        hin = hout;
    }
    final_kernel<<<NNODES / 4, 256, 0, stream>>>(hin, l1w, l1b, out);
}